// Round 4
// baseline (171.432 us; speedup 1.0000x reference)
//
#include <hip/hip_runtime.h>
#include <cstdint>
#include <cstddef>

#define BATCH 1024
#define SEQL  128
#define DIM   768
#define HID   256
#define KIN1  1536
#define BN_EPS 1e-5f

typedef unsigned short u16;
typedef __attribute__((ext_vector_type(8))) short short8;
typedef __attribute__((ext_vector_type(4))) float f32x4;

__device__ __forceinline__ u16 f2bf(float f) {
  uint32_t u = __float_as_uint(f);
  return (u16)((u + 0x7fffu + ((u >> 16) & 1u)) >> 16);  // RNE, finite inputs
}
__device__ __forceinline__ float kred(float v) {  // reduce over kgrp lanes (lane bits 4,5)
  v += __shfl_xor(v, 16);
  v += __shfl_xor(v, 32);
  return v;
}

// ---------------- 1. pool + weight-prep fused ----------------
// blocks 0..223: f32->bf16 weight conversion (first, so it hides under pool)
// blocks 224..2271: ragged mean pool
#define PREP_BLK 224
#define NW1Q (DIM * KIN1 / 4)        // 294912 float4s
#define NWQ  (NW1Q + HID * DIM / 4)  // 344064

__global__ __launch_bounds__(192) void pool_prep_kernel(
    const float* __restrict__ uf, const float* __restrict__ hf,
    const int* __restrict__ ul, const int* __restrict__ hl,
    const float* __restrict__ w1, const float* __restrict__ w2,
    u16* __restrict__ xb, u16* __restrict__ w1b, u16* __restrict__ w2b) {
  const int id = blockIdx.x;
  const int t = threadIdx.x;  // 0..191
  if (id >= PREP_BLK) {
    const int job = id - PREP_BLK;
    const int b = job >> 1;
    const int which = job & 1;
    const f32x4* src = (const f32x4*)((which ? hf : uf) + (size_t)b * (SEQL * DIM));
    const int len = which ? hl[b] : ul[b];
    f32x4 a0 = (f32x4){0.f, 0.f, 0.f, 0.f}, a1 = a0, a2 = a0, a3 = a0;
    int l = 0;
    for (; l + 8 <= len; l += 8) {
      f32x4 v0 = src[(size_t)(l + 0) * 192 + t];
      f32x4 v1 = src[(size_t)(l + 1) * 192 + t];
      f32x4 v2 = src[(size_t)(l + 2) * 192 + t];
      f32x4 v3 = src[(size_t)(l + 3) * 192 + t];
      f32x4 v4 = src[(size_t)(l + 4) * 192 + t];
      f32x4 v5 = src[(size_t)(l + 5) * 192 + t];
      f32x4 v6 = src[(size_t)(l + 6) * 192 + t];
      f32x4 v7 = src[(size_t)(l + 7) * 192 + t];
      a0 += v0; a1 += v1; a2 += v2; a3 += v3;
      a0 += v4; a1 += v5; a2 += v6; a3 += v7;
    }
    for (; l < len; ++l) a0 += src[(size_t)l * 192 + t];
    a0 += a1; a2 += a3; a0 += a2;
    const float s = 1.f / (float)len;
    ushort4 o = make_ushort4(f2bf(a0[0] * s), f2bf(a0[1] * s), f2bf(a0[2] * s), f2bf(a0[3] * s));
    *(ushort4*)(xb + (size_t)b * KIN1 + which * DIM + t * 4) = o;
  } else {
    const int j = id;
    const int base = j * 192 + t;  // stride PREP_BLK*192 = 43008
#pragma unroll
    for (int s = 0; s < 8; ++s) {
      const int i = base + s * (PREP_BLK * 192);
      if (i < NW1Q) {
        f32x4 v = ((const f32x4*)w1)[i];
        ((ushort4*)w1b)[i] = make_ushort4(f2bf(v[0]), f2bf(v[1]), f2bf(v[2]), f2bf(v[3]));
      } else {
        const int i2 = i - NW1Q;
        f32x4 v = ((const f32x4*)w2)[i2];
        ((ushort4*)w2b)[i2] = make_ushort4(f2bf(v[0]), f2bf(v[1]), f2bf(v[2]), f2bf(v[3]));
      }
    }
  }
}

// ---------------- 2. fused gemm1 -> gemm2 -> fc3, manual grid barriers ----------------
#define LDT 72  // padded row stride in u16

__device__ __forceinline__ void grid_barrier(unsigned* cnt, unsigned nblk) {
  __syncthreads();
  if (threadIdx.x == 0) {
    __threadfence();  // release: drain writes, device scope
    atomicAdd(cnt, 1u);
    while (__hip_atomic_load(cnt, __ATOMIC_RELAXED, __HIP_MEMORY_SCOPE_AGENT) < nblk)
      __builtin_amdgcn_s_sleep(2);
    __threadfence();  // acquire
  }
  __syncthreads();
}

__global__ __launch_bounds__(256, 1) void fused_tail_kernel(
    const u16* __restrict__ A, const u16* __restrict__ W1,
    const u16* __restrict__ W2,
    const float* __restrict__ b1, const float* __restrict__ g1v, const float* __restrict__ be1,
    const float* __restrict__ b2, const float* __restrict__ g2v, const float* __restrict__ be2,
    const float* __restrict__ w3, const float* __restrict__ b3,
    float* __restrict__ y1, float* __restrict__ p1,
    float* __restrict__ y2, float* __restrict__ p2,
    unsigned* __restrict__ cnt, float* __restrict__ out) {
  __shared__ alignas(16) char smem[38912];
  const int tid = threadIdx.x, lane = tid & 63, wv = tid >> 6;
  const int wr = wv >> 1, wc = wv & 1;
  const int r16 = lane & 15, kgrp = lane >> 4;
  const int sr = tid >> 3, sc8 = (tid & 7) * 8;

  // ======== phase 1: gemm1 (blocks 0..191): y1 = xb @ w1b^T + b1, partials p1 ========
  if (blockIdx.x < 192) {
    u16* lA = (u16*)smem;                                    // 2 x 64*LDT u16 = 18432 B
    u16* lB = (u16*)(smem + 18432);                          // 18432 B
    float (*red)[64][2] = (float(*)[64][2])(smem + 36864);   // 1024 B
    const int K = KIN1, N = DIM;
    const int d = blockIdx.x;
    const int g = d & 7, j = d >> 3;
    const int bm = (g >> 1) * 4 + (j & 3);   // 0..15
    const int bn = (g & 1) * 6 + (j >> 2);   // 0..11

    f32x4 acc[2][2];
#pragma unroll
    for (int mi = 0; mi < 2; ++mi)
#pragma unroll
      for (int ni = 0; ni < 2; ++ni) acc[mi][ni] = (f32x4){0.f, 0.f, 0.f, 0.f};

    const u16* Ab = A + (size_t)bm * 64 * K;
    const u16* Wb = W1 + (size_t)bn * 64 * K;

    uint4 ra0, ra1, rb0, rb1;
#define G1_LOAD(k0)                                              \
  ra0 = *(const uint4*)(Ab + (size_t)sr * K + (k0) + sc8);       \
  ra1 = *(const uint4*)(Ab + (size_t)(sr + 32) * K + (k0) + sc8);\
  rb0 = *(const uint4*)(Wb + (size_t)sr * K + (k0) + sc8);       \
  rb1 = *(const uint4*)(Wb + (size_t)(sr + 32) * K + (k0) + sc8);
#define G1_WRITE(buf)                                            \
  *(uint4*)(lA + (buf) * (64 * LDT) + sr * LDT + sc8) = ra0;     \
  *(uint4*)(lA + (buf) * (64 * LDT) + (sr + 32) * LDT + sc8) = ra1; \
  *(uint4*)(lB + (buf) * (64 * LDT) + sr * LDT + sc8) = rb0;     \
  *(uint4*)(lB + (buf) * (64 * LDT) + (sr + 32) * LDT + sc8) = rb1;

    G1_LOAD(0)
    G1_WRITE(0)
    __syncthreads();
    const int nk = K / 64;  // 24
    for (int ti = 0; ti < nk; ++ti) {
      const int cur = ti & 1;
      const bool more = (ti + 1 < nk);
      if (more) { G1_LOAD((ti + 1) * 64) }
#pragma unroll
      for (int kk = 0; kk < 2; ++kk) {
        const int koff = (kk * 4 + kgrp) * 8;
        const u16* lac = lA + cur * (64 * LDT);
        const u16* lbc = lB + cur * (64 * LDT);
        short8 af0 = *(const short8*)(lac + (wr * 32 + r16) * LDT + koff);
        short8 af1 = *(const short8*)(lac + (wr * 32 + 16 + r16) * LDT + koff);
        short8 bf0 = *(const short8*)(lbc + (wc * 32 + r16) * LDT + koff);
        short8 bf1 = *(const short8*)(lbc + (wc * 32 + 16 + r16) * LDT + koff);
        acc[0][0] = __builtin_amdgcn_mfma_f32_16x16x32_bf16(af0, bf0, acc[0][0], 0, 0, 0);
        acc[0][1] = __builtin_amdgcn_mfma_f32_16x16x32_bf16(af0, bf1, acc[0][1], 0, 0, 0);
        acc[1][0] = __builtin_amdgcn_mfma_f32_16x16x32_bf16(af1, bf0, acc[1][0], 0, 0, 0);
        acc[1][1] = __builtin_amdgcn_mfma_f32_16x16x32_bf16(af1, bf1, acc[1][1], 0, 0, 0);
      }
      if (more) { G1_WRITE(cur ^ 1) }
      __syncthreads();
    }
#undef G1_LOAD
#undef G1_WRITE

#pragma unroll
    for (int ni = 0; ni < 2; ++ni) {
      const int col = bn * 64 + wc * 32 + ni * 16 + r16;
      const float bv = b1[col];
      float s = 0.f, s2 = 0.f;
#pragma unroll
      for (int mi = 0; mi < 2; ++mi)
#pragma unroll
        for (int rg = 0; rg < 4; ++rg) {
          const int row = bm * 64 + wr * 32 + mi * 16 + kgrp * 4 + rg;
          const float v = acc[mi][ni][rg] + bv;
          y1[(size_t)row * N + col] = v;
          s += v; s2 += v * v;
        }
      s = kred(s); s2 = kred(s2);
      if (lane < 16) {
        red[wr][wc * 32 + ni * 16 + r16][0] = s;
        red[wr][wc * 32 + ni * 16 + r16][1] = s2;
      }
    }
    __syncthreads();
    if (tid < 128) {
      const int col = tid >> 1, wh = tid & 1;
      p1[((size_t)bm * DIM + bn * 64 + col) * 2 + wh] = red[0][col][wh] + red[1][col][wh];
    }
  }

  grid_barrier(cnt, 256);

  // ======== phase 2: gemm2 (all 256 blocks): y2 = relu(bn1(y1)) @ w2b^T + b2, partials p2 ========
  {
    u16* lA = (u16*)smem;                                    // 2 x 32*LDT = 9216 B
    u16* lB = (u16*)(smem + 9216);                           // 9216 B
    float* sS = (float*)(smem + 18432);                      // 3072 B
    float* sH = (float*)(smem + 21504);                      // 3072 B
    float (*red)[32][2] = (float(*)[32][2])(smem + 24576);   // 512 B
    const int K = DIM, N = HID;
    const int d = blockIdx.x;
    const int g8 = d & 7, j = d >> 3;     // XCD chunk: 4bm x 8bn per XCD
    const int bm = g8 * 4 + (j & 3);      // 0..31
    const int bn = j >> 2;                // 0..7

    for (int c = tid; c < DIM; c += 256) {
      float s = 0.f, s2 = 0.f;
#pragma unroll
      for (int i = 0; i < 16; ++i) {
        float2 pv = *(const float2*)(p1 + ((size_t)i * DIM + c) * 2);
        s += pv.x; s2 += pv.y;
      }
      const float m = s * (1.f / BATCH);
      const float var = s2 * (1.f / BATCH) - m * m;
      const float r = rsqrtf(var + BN_EPS);
      const float scl = r * g1v[c];
      sS[c] = scl;
      sH[c] = be1[c] - m * scl;
    }
    __syncthreads();

    f32x4 acc = (f32x4){0.f, 0.f, 0.f, 0.f};
    const float* Ab = y1 + (size_t)bm * 32 * K;
    const u16* Wb = W2 + (size_t)bn * 32 * K;

    f32x4 va0, va1;
    uint4 rbq;
#define G2_LOAD(k0)                                           \
  va0 = *(const f32x4*)(Ab + (size_t)sr * K + (k0) + sc8);    \
  va1 = *(const f32x4*)(Ab + (size_t)sr * K + (k0) + sc8 + 4);\
  rbq = *(const uint4*)(Wb + (size_t)sr * K + (k0) + sc8);

    auto pack_write = [&](int buf, int k0) {
      union { ushort us[8]; uint4 q; } pk;
#pragma unroll
      for (int jj = 0; jj < 4; ++jj) {
        pk.us[jj]     = f2bf(fmaxf(0.f, va0[jj] * sS[k0 + sc8 + jj] + sH[k0 + sc8 + jj]));
        pk.us[4 + jj] = f2bf(fmaxf(0.f, va1[jj] * sS[k0 + sc8 + 4 + jj] + sH[k0 + sc8 + 4 + jj]));
      }
      *(uint4*)(lA + buf * (32 * LDT) + sr * LDT + sc8) = pk.q;
      *(uint4*)(lB + buf * (32 * LDT) + sr * LDT + sc8) = rbq;
    };

    G2_LOAD(0)
    pack_write(0, 0);
    __syncthreads();
    const int nk = K / 64;  // 12
    for (int ti = 0; ti < nk; ++ti) {
      const int cur = ti & 1;
      const bool more = (ti + 1 < nk);
      if (more) { G2_LOAD((ti + 1) * 64) }
#pragma unroll
      for (int kk = 0; kk < 2; ++kk) {
        const int koff = (kk * 4 + kgrp) * 8;
        short8 af0 = *(const short8*)(lA + cur * (32 * LDT) + (wr * 16 + r16) * LDT + koff);
        short8 bf0 = *(const short8*)(lB + cur * (32 * LDT) + (wc * 16 + r16) * LDT + koff);
        acc = __builtin_amdgcn_mfma_f32_16x16x32_bf16(af0, bf0, acc, 0, 0, 0);
      }
      if (more) pack_write(cur ^ 1, (ti + 1) * 64);
      __syncthreads();
    }
#undef G2_LOAD

    {
      const int col = bn * 32 + wc * 16 + r16;
      const float bv = b2[col];
      float s = 0.f, s2 = 0.f;
#pragma unroll
      for (int rg = 0; rg < 4; ++rg) {
        const int row = bm * 32 + wr * 16 + kgrp * 4 + rg;
        const float v = acc[rg] + bv;
        y2[(size_t)row * N + col] = v;
        s += v; s2 += v * v;
      }
      s = kred(s); s2 = kred(s2);
      if (lane < 16) {
        red[wr][wc * 16 + r16][0] = s;
        red[wr][wc * 16 + r16][1] = s2;
      }
    }
    __syncthreads();
    if (tid < 64) {
      const int col = tid >> 1, wh = tid & 1;
      p2[((size_t)bm * HID + bn * 32 + col) * 2 + wh] = red[0][col][wh] + red[1][col][wh];
    }
  }

  grid_barrier(cnt + 1, 256);

  // ======== phase 3: fc3 (all 256 blocks, 4 rows each) ========
  {
    float* sS = (float*)smem;
    float* sH = (float*)(smem + 1024);
    {
      const int c = tid;
      float s = 0.f, s2 = 0.f;
#pragma unroll
      for (int i = 0; i < 32; ++i) {
        float2 pv = *(const float2*)(p2 + ((size_t)i * HID + c) * 2);
        s += pv.x; s2 += pv.y;
      }
      const float m = s * (1.f / BATCH);
      const float var = s2 * (1.f / BATCH) - m * m;
      const float r = rsqrtf(var + BN_EPS);
      const float scl = r * g2v[c];
      sS[c] = scl;
      sH[c] = be2[c] - m * scl;
    }
    __syncthreads();
    const int row = blockIdx.x * 4 + (tid >> 6);
    f32x4 xv = *(const f32x4*)(y2 + (size_t)row * HID + lane * 4);
    f32x4 sc = *(const f32x4*)&sS[lane * 4];
    f32x4 sh = *(const f32x4*)&sH[lane * 4];
    f32x4 wv = *(const f32x4*)(w3 + lane * 4);
    float dsum = 0.f;
#pragma unroll
    for (int jj = 0; jj < 4; ++jj) dsum += fmaxf(0.f, xv[jj] * sc[jj] + sh[jj]) * wv[jj];
#pragma unroll
    for (int off = 32; off > 0; off >>= 1) dsum += __shfl_xor(dsum, off);
    if (lane == 0) out[row] = 1.f / (1.f + expf(-(dsum + b3[0])));
  }
}

// ---------------- launch ----------------
extern "C" void kernel_launch(void* const* d_in, const int* in_sizes, int n_in,
                              void* d_out, int out_size, void* d_ws, size_t ws_size,
                              hipStream_t stream) {
  const float* uf   = (const float*)d_in[0];
  const float* hf   = (const float*)d_in[1];
  const int*   ul   = (const int*)d_in[2];
  const int*   hl   = (const int*)d_in[3];
  const float* fc1w = (const float*)d_in[4];
  const float* fc1b = (const float*)d_in[5];
  const float* bn1g = (const float*)d_in[6];
  const float* bn1b = (const float*)d_in[7];
  const float* fc2w = (const float*)d_in[8];
  const float* fc2b = (const float*)d_in[9];
  const float* bn2g = (const float*)d_in[10];
  const float* bn2b = (const float*)d_in[11];
  const float* fc3w = (const float*)d_in[12];
  const float* fc3b = (const float*)d_in[13];
  float* out = (float*)d_out;

  char* ws = (char*)d_ws;
  u16*   xb  = (u16*)  (ws + 0);          // 1024*1536 bf16  (3145728 B)
  u16*   w1b = (u16*)  (ws + 3145728);    // 768*1536 bf16   (2359296 B)
  u16*   w2b = (u16*)  (ws + 5505024);    // 256*768 bf16    (393216 B)
  float* y1  = (float*)(ws + 5898240);    // 1024*768 f32    (3145728 B)
  float* y2  = (float*)(ws + 9043968);    // 1024*256 f32    (1048576 B)
  float* p1  = (float*)(ws + 10092544);   // 16*768*2 f32    (98304 B)
  float* p2  = (float*)(ws + 10190848);   // 32*256*2 f32    (65536 B)
  unsigned* cnt = (unsigned*)(ws + 10256384);  // 2 barrier counters

  hipMemsetAsync(cnt, 0, 8, stream);
  pool_prep_kernel<<<PREP_BLK + 2048, 192, 0, stream>>>(uf, hf, ul, hl, fc1w, fc2w, xb, w1b, w2b);
  fused_tail_kernel<<<256, 256, 0, stream>>>(xb, w1b, w2b, fc1b, bn1g, bn1b,
                                             fc2b, bn2g, bn2b, fc3w, fc3b,
                                             y1, p1, y2, p2, cnt, out);
}

// Round 5
// 109.831 us; speedup vs baseline: 1.5609x; 1.5609x over previous
//
#include <hip/hip_runtime.h>
#include <cstdint>
#include <cstddef>

#define BATCH 1024
#define SEQL  128
#define DIM   768
#define HID   256
#define KIN1  1536
#define BN_EPS 1e-5f

typedef unsigned short u16;
typedef __attribute__((ext_vector_type(8))) short short8;
typedef __attribute__((ext_vector_type(4))) float f32x4;

__device__ __forceinline__ u16 f2bf(float f) {
  uint32_t u = __float_as_uint(f);
  return (u16)((u + 0x7fffu + ((u >> 16) & 1u)) >> 16);  // RNE, finite inputs
}
__device__ __forceinline__ f32x4 ntl(const f32x4* p) { return __builtin_nontemporal_load(p); }
__device__ __forceinline__ float kred(float v) {  // reduce over kgrp lanes (lane bits 4,5)
  v += __shfl_xor(v, 16);
  v += __shfl_xor(v, 32);
  return v;
}

// ---------------- 1. pool + weight-prep fused ----------------
// blocks 0..4095: ragged mean pool, one (sample, tensor, col-half) per block
//                 (col-split halves the max straggler block: <=192 KB each)
// blocks 4096..4543: f32->bf16 weight conversion (rides free under pool BW)
#define POOL_BLK 4096
#define PREP_BLK 448
#define NW1Q (DIM * KIN1 / 4)        // 294912 float4s
#define NWQ  (NW1Q + HID * DIM / 4)  // 344064

__global__ __launch_bounds__(96) void pool_prep_kernel(
    const float* __restrict__ uf, const float* __restrict__ hf,
    const int* __restrict__ ul, const int* __restrict__ hl,
    const float* __restrict__ w1, const float* __restrict__ w2,
    u16* __restrict__ xb, u16* __restrict__ w1b, u16* __restrict__ w2b) {
  const int id = blockIdx.x;
  const int t = threadIdx.x;  // 0..95
  if (id < POOL_BLK) {
    const int b = id >> 2;
    const int which = (id >> 1) & 1;
    const int half = id & 1;
    const f32x4* src = (const f32x4*)((which ? hf : uf) + (size_t)b * (SEQL * DIM)) + half * 96;
    const int len = which ? hl[b] : ul[b];
    f32x4 a0 = (f32x4){0.f, 0.f, 0.f, 0.f}, a1 = a0, a2 = a0, a3 = a0;
    int l = 0;
    for (; l + 8 <= len; l += 8) {
      f32x4 v0 = ntl(src + (size_t)(l + 0) * 192 + t);
      f32x4 v1 = ntl(src + (size_t)(l + 1) * 192 + t);
      f32x4 v2 = ntl(src + (size_t)(l + 2) * 192 + t);
      f32x4 v3 = ntl(src + (size_t)(l + 3) * 192 + t);
      f32x4 v4 = ntl(src + (size_t)(l + 4) * 192 + t);
      f32x4 v5 = ntl(src + (size_t)(l + 5) * 192 + t);
      f32x4 v6 = ntl(src + (size_t)(l + 6) * 192 + t);
      f32x4 v7 = ntl(src + (size_t)(l + 7) * 192 + t);
      a0 += v0; a1 += v1; a2 += v2; a3 += v3;
      a0 += v4; a1 += v5; a2 += v6; a3 += v7;
    }
    for (; l < len; ++l) a0 += ntl(src + (size_t)l * 192 + t);
    a0 += a1; a2 += a3; a0 += a2;
    const float s = 1.f / (float)len;
    ushort4 o = make_ushort4(f2bf(a0[0] * s), f2bf(a0[1] * s), f2bf(a0[2] * s), f2bf(a0[3] * s));
    *(ushort4*)(xb + (size_t)b * KIN1 + which * DIM + half * 384 + t * 4) = o;
  } else {
    const int j = id - POOL_BLK;
    const int base = j * 96 + t;  // stride PREP_BLK*96 = 43008
#pragma unroll
    for (int s = 0; s < 8; ++s) {
      const int i = base + s * (PREP_BLK * 96);
      if (i < NW1Q) {
        f32x4 v = ((const f32x4*)w1)[i];
        ((ushort4*)w1b)[i] = make_ushort4(f2bf(v[0]), f2bf(v[1]), f2bf(v[2]), f2bf(v[3]));
      } else {
        const int i2 = i - NW1Q;
        f32x4 v = ((const f32x4*)w2)[i2];
        ((ushort4*)w2b)[i2] = make_ushort4(f2bf(v[0]), f2bf(v[1]), f2bf(v[2]), f2bf(v[3]));
      }
    }
  }
}

// ---------------- 2. gemm1: y1 = xb @ w1b^T + b1; + column partials ----------------
// BM=64, BN=64, BK=64; 256 thr = 4 waves (2x2), wave tile 32x32 (2x2 frags)
// double-buffered LDS, one barrier/iter; XCD chunk swizzle (4bm x 6bn per XCD)
#define LDT 72  // padded row stride in u16

__global__ __launch_bounds__(256) void gemm1_kernel(
    const u16* __restrict__ A, const u16* __restrict__ W,
    const float* __restrict__ bias, float* __restrict__ y, float* __restrict__ p1) {
  __shared__ u16 lA[2][64 * LDT];
  __shared__ u16 lB[2][64 * LDT];
  __shared__ float red[2][64][2];
  const int K = KIN1, N = DIM;
  const int tid = threadIdx.x, lane = tid & 63, wv = tid >> 6;
  const int wr = wv >> 1, wc = wv & 1;
  const int r16 = lane & 15, kgrp = lane >> 4;
  const int d = blockIdx.x;
  const int g = d & 7, j = d >> 3;
  const int bm = (g >> 1) * 4 + (j & 3);   // 0..15
  const int bn = (g & 1) * 6 + (j >> 2);   // 0..11
  const int sr = tid >> 3, sc8 = (tid & 7) * 8;

  f32x4 acc[2][2];
#pragma unroll
  for (int mi = 0; mi < 2; ++mi)
#pragma unroll
    for (int ni = 0; ni < 2; ++ni) acc[mi][ni] = (f32x4){0.f, 0.f, 0.f, 0.f};

  const u16* Ab = A + (size_t)bm * 64 * K;
  const u16* Wb = W + (size_t)bn * 64 * K;

  uint4 ra0, ra1, rb0, rb1;
#define G1_LOAD(k0)                                              \
  ra0 = *(const uint4*)(Ab + (size_t)sr * K + (k0) + sc8);       \
  ra1 = *(const uint4*)(Ab + (size_t)(sr + 32) * K + (k0) + sc8);\
  rb0 = *(const uint4*)(Wb + (size_t)sr * K + (k0) + sc8);       \
  rb1 = *(const uint4*)(Wb + (size_t)(sr + 32) * K + (k0) + sc8);
#define G1_WRITE(buf)                                \
  *(uint4*)(lA[buf] + sr * LDT + sc8) = ra0;         \
  *(uint4*)(lA[buf] + (sr + 32) * LDT + sc8) = ra1;  \
  *(uint4*)(lB[buf] + sr * LDT + sc8) = rb0;         \
  *(uint4*)(lB[buf] + (sr + 32) * LDT + sc8) = rb1;

  G1_LOAD(0)
  G1_WRITE(0)
  __syncthreads();
  const int nk = K / 64;  // 24
  for (int ti = 0; ti < nk; ++ti) {
    const int cur = ti & 1;
    const bool more = (ti + 1 < nk);
    if (more) { G1_LOAD((ti + 1) * 64) }
#pragma unroll
    for (int kk = 0; kk < 2; ++kk) {
      const int koff = (kk * 4 + kgrp) * 8;
      short8 af0 = *(const short8*)(lA[cur] + (wr * 32 + r16) * LDT + koff);
      short8 af1 = *(const short8*)(lA[cur] + (wr * 32 + 16 + r16) * LDT + koff);
      short8 bf0 = *(const short8*)(lB[cur] + (wc * 32 + r16) * LDT + koff);
      short8 bf1 = *(const short8*)(lB[cur] + (wc * 32 + 16 + r16) * LDT + koff);
      acc[0][0] = __builtin_amdgcn_mfma_f32_16x16x32_bf16(af0, bf0, acc[0][0], 0, 0, 0);
      acc[0][1] = __builtin_amdgcn_mfma_f32_16x16x32_bf16(af0, bf1, acc[0][1], 0, 0, 0);
      acc[1][0] = __builtin_amdgcn_mfma_f32_16x16x32_bf16(af1, bf0, acc[1][0], 0, 0, 0);
      acc[1][1] = __builtin_amdgcn_mfma_f32_16x16x32_bf16(af1, bf1, acc[1][1], 0, 0, 0);
    }
    if (more) { G1_WRITE(cur ^ 1) }
    __syncthreads();
  }

#pragma unroll
  for (int ni = 0; ni < 2; ++ni) {
    const int col = bn * 64 + wc * 32 + ni * 16 + r16;
    const float bv = bias[col];
    float s = 0.f, s2 = 0.f;
#pragma unroll
    for (int mi = 0; mi < 2; ++mi)
#pragma unroll
      for (int rg = 0; rg < 4; ++rg) {
        const int row = bm * 64 + wr * 32 + mi * 16 + kgrp * 4 + rg;
        const float v = acc[mi][ni][rg] + bv;
        y[(size_t)row * N + col] = v;
        s += v; s2 += v * v;
      }
    s = kred(s); s2 = kred(s2);
    if (lane < 16) {
      red[wr][wc * 32 + ni * 16 + r16][0] = s;
      red[wr][wc * 32 + ni * 16 + r16][1] = s2;
    }
  }
  __syncthreads();
  if (tid < 128) {
    const int col = tid >> 1, wh = tid & 1;
    p1[((size_t)bm * DIM + bn * 64 + col) * 2 + wh] = red[0][col][wh] + red[1][col][wh];
  }
}

// ---------------- 3. gemm2: y2 = relu(bn1(y1)) @ w2b^T + b2; + column partials ----------------
// BM=32, BN=32 -> 256 blocks (full chip); 4 waves 2x2, wave tile 16x16; BN1 in A-staging
__global__ __launch_bounds__(256) void gemm2_kernel(
    const float* __restrict__ y1, const u16* __restrict__ W,
    const float* __restrict__ bias, const float* __restrict__ g, const float* __restrict__ be,
    const float* __restrict__ p1, float* __restrict__ y2, float* __restrict__ p2) {
  __shared__ u16 lA[2][32 * LDT];
  __shared__ u16 lB[2][32 * LDT];
  __shared__ float sS[DIM], sH[DIM];
  __shared__ float red[2][32][2];
  const int K = DIM, N = HID;
  const int tid = threadIdx.x, lane = tid & 63, wv = tid >> 6;
  const int wr = wv >> 1, wc = wv & 1;
  const int r16 = lane & 15, kgrp = lane >> 4;
  const int d = blockIdx.x;
  const int g8 = d & 7, j = d >> 3;     // XCD chunk: 4bm x 8bn per XCD
  const int bm = g8 * 4 + (j & 3);      // 0..31
  const int bn = j >> 2;                // 0..7
  const int sr = tid >> 3, sc8 = (tid & 7) * 8;

  for (int c = tid; c < DIM; c += 256) {
    float s = 0.f, s2 = 0.f;
#pragma unroll
    for (int i = 0; i < 16; ++i) {
      float2 pv = *(const float2*)(p1 + ((size_t)i * DIM + c) * 2);
      s += pv.x; s2 += pv.y;
    }
    const float m = s * (1.f / BATCH);
    const float var = s2 * (1.f / BATCH) - m * m;
    const float r = rsqrtf(var + BN_EPS);
    const float scl = r * g[c];
    sS[c] = scl;
    sH[c] = be[c] - m * scl;
  }
  __syncthreads();

  f32x4 acc = (f32x4){0.f, 0.f, 0.f, 0.f};
  const float* Ab = y1 + (size_t)bm * 32 * K;
  const u16* Wb = W + (size_t)bn * 32 * K;

  f32x4 va0, va1;
  uint4 rbq;
#define G2_LOAD(k0)                                          \
  va0 = *(const f32x4*)(Ab + (size_t)sr * K + (k0) + sc8);   \
  va1 = *(const f32x4*)(Ab + (size_t)sr * K + (k0) + sc8 + 4);\
  rbq = *(const uint4*)(Wb + (size_t)sr * K + (k0) + sc8);

  auto pack_write = [&](int buf, int k0) {
    union { ushort us[8]; uint4 q; } pk;
#pragma unroll
    for (int jj = 0; jj < 4; ++jj) {
      pk.us[jj]     = f2bf(fmaxf(0.f, va0[jj] * sS[k0 + sc8 + jj] + sH[k0 + sc8 + jj]));
      pk.us[4 + jj] = f2bf(fmaxf(0.f, va1[jj] * sS[k0 + sc8 + 4 + jj] + sH[k0 + sc8 + 4 + jj]));
    }
    *(uint4*)(lA[buf] + sr * LDT + sc8) = pk.q;
    *(uint4*)(lB[buf] + sr * LDT + sc8) = rbq;
  };

  G2_LOAD(0)
  pack_write(0, 0);
  __syncthreads();
  const int nk = K / 64;  // 12
  for (int ti = 0; ti < nk; ++ti) {
    const int cur = ti & 1;
    const bool more = (ti + 1 < nk);
    if (more) { G2_LOAD((ti + 1) * 64) }
#pragma unroll
    for (int kk = 0; kk < 2; ++kk) {
      const int koff = (kk * 4 + kgrp) * 8;
      short8 af0 = *(const short8*)(lA[cur] + (wr * 16 + r16) * LDT + koff);
      short8 bf0 = *(const short8*)(lB[cur] + (wc * 16 + r16) * LDT + koff);
      acc = __builtin_amdgcn_mfma_f32_16x16x32_bf16(af0, bf0, acc, 0, 0, 0);
    }
    if (more) pack_write(cur ^ 1, (ti + 1) * 64);
    __syncthreads();
  }

  {
    const int col = bn * 32 + wc * 16 + r16;
    const float bv = bias[col];
    float s = 0.f, s2 = 0.f;
#pragma unroll
    for (int rg = 0; rg < 4; ++rg) {
      const int row = bm * 32 + wr * 16 + kgrp * 4 + rg;
      const float v = acc[rg] + bv;
      y2[(size_t)row * N + col] = v;
      s += v; s2 += v * v;
    }
    s = kred(s); s2 = kred(s2);
    if (lane < 16) {
      red[wr][wc * 16 + r16][0] = s;
      red[wr][wc * 16 + r16][1] = s2;
    }
  }
  __syncthreads();
  if (tid < 64) {
    const int col = tid >> 1, wh = tid & 1;
    p2[((size_t)bm * HID + bn * 32 + col) * 2 + wh] = red[0][col][wh] + red[1][col][wh];
  }
}

// ---------------- 4. fc3: out = sigmoid(relu(bn2(y2)) @ w3^T + b3) ----------------
__global__ __launch_bounds__(256) void fc3_kernel(
    const float* __restrict__ y2, const float* __restrict__ p2,
    const float* __restrict__ g, const float* __restrict__ be,
    const float* __restrict__ w3, const float* __restrict__ b3, float* __restrict__ out) {
  __shared__ float sS[HID], sH[HID];
  const int tid = threadIdx.x;
  {
    const int c = tid;
    float s = 0.f, s2 = 0.f;
#pragma unroll
    for (int i = 0; i < 32; ++i) {
      float2 pv = *(const float2*)(p2 + ((size_t)i * HID + c) * 2);
      s += pv.x; s2 += pv.y;
    }
    const float m = s * (1.f / BATCH);
    const float var = s2 * (1.f / BATCH) - m * m;
    const float r = rsqrtf(var + BN_EPS);
    const float scl = r * g[c];
    sS[c] = scl;
    sH[c] = be[c] - m * scl;
  }
  __syncthreads();
  const int row = blockIdx.x * 4 + (tid >> 6);
  const int lane = tid & 63;
  f32x4 xv = *(const f32x4*)(y2 + (size_t)row * HID + lane * 4);
  f32x4 sc = *(const f32x4*)&sS[lane * 4];
  f32x4 sh = *(const f32x4*)&sH[lane * 4];
  f32x4 wv = *(const f32x4*)(w3 + lane * 4);
  float dsum = 0.f;
#pragma unroll
  for (int jj = 0; jj < 4; ++jj) dsum += fmaxf(0.f, xv[jj] * sc[jj] + sh[jj]) * wv[jj];
#pragma unroll
  for (int off = 32; off > 0; off >>= 1) dsum += __shfl_xor(dsum, off);
  if (lane == 0) out[row] = 1.f / (1.f + expf(-(dsum + b3[0])));
}

// ---------------- launch ----------------
extern "C" void kernel_launch(void* const* d_in, const int* in_sizes, int n_in,
                              void* d_out, int out_size, void* d_ws, size_t ws_size,
                              hipStream_t stream) {
  const float* uf   = (const float*)d_in[0];
  const float* hf   = (const float*)d_in[1];
  const int*   ul   = (const int*)d_in[2];
  const int*   hl   = (const int*)d_in[3];
  const float* fc1w = (const float*)d_in[4];
  const float* fc1b = (const float*)d_in[5];
  const float* bn1g = (const float*)d_in[6];
  const float* bn1b = (const float*)d_in[7];
  const float* fc2w = (const float*)d_in[8];
  const float* fc2b = (const float*)d_in[9];
  const float* bn2g = (const float*)d_in[10];
  const float* bn2b = (const float*)d_in[11];
  const float* fc3w = (const float*)d_in[12];
  const float* fc3b = (const float*)d_in[13];
  float* out = (float*)d_out;

  char* ws = (char*)d_ws;
  u16*   xb  = (u16*)  (ws + 0);          // 1024*1536 bf16  (3145728 B)
  u16*   w1b = (u16*)  (ws + 3145728);    // 768*1536 bf16   (2359296 B)
  u16*   w2b = (u16*)  (ws + 5505024);    // 256*768 bf16    (393216 B)
  float* y1  = (float*)(ws + 5898240);    // 1024*768 f32    (3145728 B)
  float* y2  = (float*)(ws + 9043968);    // 1024*256 f32    (1048576 B)
  float* p1  = (float*)(ws + 10092544);   // 16*768*2 f32    (98304 B)
  float* p2  = (float*)(ws + 10190848);   // 32*256*2 f32    (65536 B)

  pool_prep_kernel<<<POOL_BLK + PREP_BLK, 96, 0, stream>>>(uf, hf, ul, hl, fc1w, fc2w, xb, w1b, w2b);
  gemm1_kernel<<<192, 256, 0, stream>>>(xb, w1b, fc1b, y1, p1);
  gemm2_kernel<<<256, 256, 0, stream>>>(y1, w2b, fc2b, bn1g, bn1b, p1, y2, p2);
  fc3_kernel<<<256, 256, 0, stream>>>(y2, p2, bn2g, bn2b, fc3w, fc3b, out);
}